// Round 3
// baseline (659.861 us; speedup 1.0000x reference)
//
#include <hip/hip_runtime.h>
#include <hip/hip_bf16.h>
#include <stdint.h>

#define N_NODES 50000
#define N_PAD   50048   // 391 * 128
#define E_EDGES 800000
#define MT      391     // row tiles of 128

typedef __bf16 bf16x8 __attribute__((ext_vector_type(8)));
typedef __bf16 bf16x4 __attribute__((ext_vector_type(4)));
typedef float  f32x4  __attribute__((ext_vector_type(4)));

// ---------------- CSR build ----------------
__global__ void count_deg(const int* __restrict__ ei, int* __restrict__ cnt) {
    int e = blockIdx.x * blockDim.x + threadIdx.x;
    if (e < E_EDGES) atomicAdd(&cnt[ei[E_EDGES + e]], 1);
}

#define SCAN_B 1024
__global__ void scan_block(const int* __restrict__ cnt, int* __restrict__ ptr,
                           int* __restrict__ bsum, int n) {
    __shared__ int buf[SCAN_B];
    int i = blockIdx.x * SCAN_B + threadIdx.x;
    int v = (i < n) ? cnt[i] : 0;
    buf[threadIdx.x] = v;
    __syncthreads();
    #pragma unroll
    for (int off = 1; off < SCAN_B; off <<= 1) {
        int t = (threadIdx.x >= (unsigned)off) ? buf[threadIdx.x - off] : 0;
        __syncthreads();
        buf[threadIdx.x] += t;
        __syncthreads();
    }
    if (i < n) ptr[i] = buf[threadIdx.x] - v;
    if (threadIdx.x == SCAN_B - 1) bsum[blockIdx.x] = buf[SCAN_B - 1];
}

__global__ void scan_bsums(int* __restrict__ bsum, int* __restrict__ boff, int nb,
                           int* __restrict__ total_out) {
    __shared__ int buf[64];
    int v = ((int)threadIdx.x < nb) ? bsum[threadIdx.x] : 0;
    buf[threadIdx.x] = v;
    __syncthreads();
    #pragma unroll
    for (int off = 1; off < 64; off <<= 1) {
        int t = (threadIdx.x >= (unsigned)off) ? buf[threadIdx.x - off] : 0;
        __syncthreads();
        buf[threadIdx.x] += t;
        __syncthreads();
    }
    if ((int)threadIdx.x < nb) boff[threadIdx.x] = buf[threadIdx.x] - v;
    if (threadIdx.x == 63) *total_out = buf[63];
}

__global__ void scan_add(int* __restrict__ ptr, const int* __restrict__ boff, int n) {
    int i = blockIdx.x * SCAN_B + threadIdx.x;
    if (i < n) ptr[i] += boff[blockIdx.x];
}

__global__ void fill_csr(const int* __restrict__ ei, const int* __restrict__ ptr,
                         int* __restrict__ cursor, int* __restrict__ col) {
    int e = blockIdx.x * blockDim.x + threadIdx.x;
    if (e < E_EDGES) {
        int dst = ei[E_EDGES + e];
        int pos = ptr[dst] + atomicAdd(&cursor[dst], 1);
        col[pos] = ei[e];
    }
}

// ---------------- one-shot fp32 -> bf16 conversion (x + all weights) -----------
#define XN      3200000
#define WTOT    983040
__global__ void cvt_all(const float* __restrict__ x,
                        const float* __restrict__ Ws1, const float* __restrict__ Ws2,
                        const float* __restrict__ Ws3, const float* __restrict__ Ws4,
                        const float* __restrict__ Wm1, const float* __restrict__ Wl1,
                        const float* __restrict__ Wm2, const float* __restrict__ Wl2,
                        __bf16* __restrict__ xb, __bf16* __restrict__ wbuf) {
    int i = blockIdx.x * blockDim.x + threadIdx.x;
    if (i < XN) { xb[i] = (__bf16)x[i]; return; }
    int j = i - XN;
    if (j >= WTOT) return;
    const float* s; int o;
    if      (j <  32768) { s = Ws1; o = j; }
    else if (j < 294912) { s = Ws2; o = j -  32768; }
    else if (j < 557056) { s = Ws3; o = j - 294912; }
    else if (j < 819200) { s = Ws4; o = j - 557056; }
    else if (j < 884736) { s = Wm1; o = j - 819200; }
    else if (j < 950272) { s = Wl1; o = j - 884736; }
    else if (j < 966656) { s = Wm2; o = j - 950272; }
    else                 { s = Wl2; o = j - 966656; }
    wbuf[j] = (__bf16)s[o];
}

// ---------------- aggregation (gather over CSR, fp32 accumulate) ---------------
__global__ void agg0_gather(const __bf16* __restrict__ xb, const int* __restrict__ ptr,
                            const int* __restrict__ col, __bf16* __restrict__ out) {
    int node = blockIdx.x * 4 + (threadIdx.x >> 6);
    int lane = threadIdx.x & 63;
    if (node >= N_PAD) return;
    long o = (long)node * 64 + lane;
    if (node >= N_NODES) { out[o] = (__bf16)0.0f; return; }
    float acc = (float)xb[o];
    int e0 = ptr[node], e1 = ptr[node + 1];
    int e = e0;
    for (; e + 8 <= e1; e += 8) {               // 8 independent loads in flight
        int c[8];
        #pragma unroll
        for (int u = 0; u < 8; ++u) c[u] = col[e + u];
        float v[8];
        #pragma unroll
        for (int u = 0; u < 8; ++u) v[u] = (float)xb[(long)c[u] * 64 + lane];
        #pragma unroll
        for (int u = 0; u < 8; ++u) acc += v[u];
    }
    for (; e < e1; ++e) acc += (float)xb[(long)col[e] * 64 + lane];
    out[o] = (__bf16)acc;
}

__global__ void aggt_gather(const __bf16* __restrict__ t, const int* __restrict__ ptr,
                            const int* __restrict__ col, const float* __restrict__ b_m1,
                            const float* __restrict__ b_l1, __bf16* __restrict__ p) {
    int node = blockIdx.x * 4 + (threadIdx.x >> 6);
    int lane = threadIdx.x & 63;
    if (node >= N_NODES) return;
    const int f0 = lane * 4;
    bf16x4 s = *(const bf16x4*)&t[(long)node * 256 + f0];
    float a0 = (float)s[0], a1 = (float)s[1], a2 = (float)s[2], a3 = (float)s[3];
    int e0 = ptr[node], e1 = ptr[node + 1];
    int e = e0;
    for (; e + 8 <= e1; e += 8) {               // 8 independent 8-B loads in flight
        int c[8];
        #pragma unroll
        for (int u = 0; u < 8; ++u) c[u] = col[e + u];
        bf16x4 v[8];
        #pragma unroll
        for (int u = 0; u < 8; ++u) v[u] = *(const bf16x4*)&t[(long)c[u] * 256 + f0];
        #pragma unroll
        for (int u = 0; u < 8; ++u) {
            a0 += (float)v[u][0]; a1 += (float)v[u][1];
            a2 += (float)v[u][2]; a3 += (float)v[u][3];
        }
    }
    for (; e < e1; ++e) {
        bf16x4 v = *(const bf16x4*)&t[(long)col[e] * 256 + f0];
        a0 += (float)v[0]; a1 += (float)v[1]; a2 += (float)v[2]; a3 += (float)v[3];
    }
    float b0, b1, b2, b3;
    if (f0 < 128) { b0 = b_m1[f0]; b1 = b_m1[f0+1]; b2 = b_m1[f0+2]; b3 = b_m1[f0+3]; }
    else          { b0 = b_l1[f0-128]; b1 = b_l1[f0-127]; b2 = b_l1[f0-126]; b3 = b_l1[f0-125]; }
    bf16x4 r;
    r[0] = (__bf16)fmaxf(a0 + b0, 0.0f);
    r[1] = (__bf16)fmaxf(a1 + b1, 0.0f);
    r[2] = (__bf16)fmaxf(a2 + b2, 0.0f);
    r[3] = (__bf16)fmaxf(a3 + b3, 0.0f);
    *(bf16x4*)&p[(long)node * 256 + f0] = r;
}

// ---------------- bf16 MFMA GEMM: C[M,N] = A[M,K] * W[N,K]^T (+bias, act) ------
// Tile: 128 rows x NT cols (NT = 128 or 256). NT=256 halves A re-reads when N=512.
__device__ __forceinline__ void gl_lds16(const __bf16* g, __bf16* l) {
    __builtin_amdgcn_global_load_lds(
        (const __attribute__((address_space(1))) uint32_t*)g,
        (__attribute__((address_space(3))) uint32_t*)l, 16, 0, 0);
}

template <int NT, int ACT, bool BIAS, bool OUT_BF16, bool MCHK>
__global__ __launch_bounds__(256) void gemm_bt(
    const __bf16* __restrict__ A, int lda, const __bf16* __restrict__ W,
    const float* __restrict__ bias, void* __restrict__ Cout, int ldc,
    int K, int Mstore) {
    // LDS [rows][32 k], per-row XOR swizzle of the 8-elem k-group:
    // element (r,k) at r*32 + (((k>>3) ^ ((r>>1)&3))<<3) + (k&7)
    __shared__ __bf16 As[128 * 32];
    __shared__ __bf16 Ws[NT * 32];
    constexpr int NFRAG = NT / 32;     // col frags per wave (wave tile 64 x NT/2)
    constexpr int WCH   = NT / 64;     // W staging chunks (16 rows) per wave

    const int tid  = threadIdx.x;
    const int wid  = tid >> 6;
    const int lane = tid & 63;
    const long blockRow = (long)blockIdx.x * 128;
    const int  blockCol = blockIdx.y * NT;
    const int wm = (wid >> 1) << 6;
    const int wn = (wid & 1) * (NT / 2);

    f32x4 acc[4][NFRAG];
    #pragma unroll
    for (int i = 0; i < 4; ++i)
        #pragma unroll
        for (int j = 0; j < NFRAG; ++j) acc[i][j] = (f32x4)0.0f;

    const int lr = lane >> 2;                        // row within 16-row chunk
    const int kg = (lane & 3) ^ ((lane >> 3) & 3);   // swizzled k-group
    const __bf16* gA0 = A + (blockRow + wid * 32 + lr) * (long)lda + kg * 8;
    const __bf16* gA1 = gA0 + 16L * lda;
    __bf16* lA0 = As + wid * 1024;
    __bf16* lA1 = lA0 + 512;
    const __bf16* gW[WCH];
    __bf16* lW[WCH];
    #pragma unroll
    for (int c = 0; c < WCH; ++c) {
        gW[c] = W + ((long)blockCol + (wid * WCH + c) * 16 + lr) * (long)K + kg * 8;
        lW[c] = Ws + (wid * WCH + c) * 512;
    }

    const int rA  = lane & 15;
    const int q   = lane >> 4;
    const int swz = ((q ^ ((rA >> 1) & 3)) << 3);

    for (int k0 = 0; k0 < K; k0 += 32) {
        gl_lds16(gA0 + k0, lA0);
        gl_lds16(gA1 + k0, lA1);
        #pragma unroll
        for (int c = 0; c < WCH; ++c) gl_lds16(gW[c] + k0, lW[c]);
        __syncthreads();

        bf16x8 af[4], bf[NFRAG];
        #pragma unroll
        for (int mi = 0; mi < 4; ++mi)
            af[mi] = *(const bf16x8*)&As[(wm + mi * 16 + rA) * 32 + swz];
        #pragma unroll
        for (int ni = 0; ni < NFRAG; ++ni)
            bf[ni] = *(const bf16x8*)&Ws[(wn + ni * 16 + rA) * 32 + swz];
        #pragma unroll
        for (int mi = 0; mi < 4; ++mi)
            #pragma unroll
            for (int ni = 0; ni < NFRAG; ++ni)
                acc[mi][ni] = __builtin_amdgcn_mfma_f32_16x16x32_bf16(
                    af[mi], bf[ni], acc[mi][ni], 0, 0, 0);
        __syncthreads();
    }

    // epilogue: C/D layout col=lane&15, row=(lane>>4)*4+reg
    const int ccol = lane & 15;
    const int crow = (lane >> 4) << 2;
    #pragma unroll
    for (int mi = 0; mi < 4; ++mi) {
        #pragma unroll
        for (int ni = 0; ni < NFRAG; ++ni) {
            long gr0 = blockRow + wm + mi * 16 + crow;
            int  gc  = blockCol + wn + ni * 16 + ccol;
            float bv = BIAS ? bias[gc] : 0.0f;
            #pragma unroll
            for (int r = 0; r < 4; ++r) {
                long gr = gr0 + r;
                if (!MCHK || gr < Mstore) {
                    float v = acc[mi][ni][r] + bv;
                    if (ACT == 1) v = (v > 0.0f) ? v : 0.1f * v;
                    else if (ACT == 2) v = fmaxf(v, 0.0f);
                    if (OUT_BF16) ((__bf16*)Cout)[gr * ldc + gc] = (__bf16)v;
                    else          ((float*)Cout)[gr * ldc + gc] = v;
                }
            }
        }
    }
}

extern "C" void kernel_launch(void* const* d_in, const int* in_sizes, int n_in,
                              void* d_out, int out_size, void* d_ws, size_t ws_size,
                              hipStream_t stream) {
    const float* x    = (const float*)d_in[0];
    const int*   ei   = (const int*)d_in[1];
    const float* W_s1 = (const float*)d_in[2];
    const float* b_s1 = (const float*)d_in[3];
    const float* W_s2 = (const float*)d_in[4];
    const float* b_s2 = (const float*)d_in[5];
    const float* W_s3 = (const float*)d_in[6];
    const float* b_s3 = (const float*)d_in[7];
    const float* W_s4 = (const float*)d_in[8];
    const float* b_s4 = (const float*)d_in[9];
    const float* W_m1 = (const float*)d_in[10];
    const float* b_m1 = (const float*)d_in[11];
    const float* W_m2 = (const float*)d_in[12];
    const float* b_m2 = (const float*)d_in[13];
    const float* W_l1 = (const float*)d_in[14];
    const float* b_l1 = (const float*)d_in[15];
    const float* W_l2 = (const float*)d_in[16];
    const float* b_l2 = (const float*)d_in[17];

    char* ws = (char*)d_ws;
    size_t off = 0;
    auto carve = [&](size_t bytes) -> void* {
        void* p = ws + off;
        off = (off + bytes + 255) & ~(size_t)255;
        return p;
    };
    int* cnt  = (int*)carve((size_t)N_NODES * 4);
    int* cur  = (int*)carve((size_t)N_NODES * 4);
    int* ptr  = (int*)carve((size_t)(N_NODES + 1) * 4);
    int* col  = (int*)carve((size_t)E_EDGES * 4);
    int* bsum = (int*)carve(64 * 4);
    int* boff = (int*)carve(64 * 4);
    __bf16* wbuf = (__bf16*)carve((size_t)WTOT * 2);
    __bf16* w1  = wbuf;
    __bf16* w2  = wbuf +  32768;
    __bf16* w3  = wbuf + 294912;
    __bf16* w4  = wbuf + 557056;
    __bf16* wml = wbuf + 819200;   // [W_m1 ; W_l1] rows, 256x512
    __bf16* wm2 = wbuf + 950272;
    __bf16* wl2 = wbuf + 966656;
    __bf16* xb    = (__bf16*)carve((size_t)XN * 2);
    __bf16* agg0b = (__bf16*)carve((size_t)N_PAD * 64 * 2);
    __bf16* B1    = (__bf16*)carve((size_t)N_PAD * 512 * 2);
    __bf16* B2    = (__bf16*)carve((size_t)N_PAD * 512 * 2);

    (void)hipMemsetAsync(cnt, 0, (size_t)N_NODES * 4, stream);
    (void)hipMemsetAsync(cur, 0, (size_t)N_NODES * 4, stream);

    // CSR build
    const int NB = (N_NODES + SCAN_B - 1) / SCAN_B;  // 49
    count_deg<<<E_EDGES / 256, 256, 0, stream>>>(ei, cnt);
    scan_block<<<NB, SCAN_B, 0, stream>>>(cnt, ptr, bsum, N_NODES);
    scan_bsums<<<1, 64, 0, stream>>>(bsum, boff, NB, &ptr[N_NODES]);
    scan_add<<<NB, SCAN_B, 0, stream>>>(ptr, boff, N_NODES);
    fill_csr<<<E_EDGES / 256, 256, 0, stream>>>(ei, ptr, cur, col);

    // one-shot conversions
    cvt_all<<<(XN + WTOT + 255) / 256, 256, 0, stream>>>(
        x, W_s1, W_s2, W_s3, W_s4, W_m1, W_l1, W_m2, W_l2, xb, wbuf);

    // first aggregation
    agg0_gather<<<N_PAD / 4, 256, 0, stream>>>(xb, ptr, col, agg0b);

    // shared MLP: 64->512->512->512->512, lrelu x3, final +b then relu
    // NT=256 tiles: A re-read 2x (not 4x) per GEMM
    gemm_bt<256, 1, true, true, false><<<dim3(MT, 2), 256, 0, stream>>>(agg0b, 64, w1, b_s1, B1, 512, 64, N_PAD);
    gemm_bt<256, 1, true, true, false><<<dim3(MT, 2), 256, 0, stream>>>(B1, 512, w2, b_s2, B2, 512, 512, N_PAD);
    gemm_bt<256, 1, true, true, false><<<dim3(MT, 2), 256, 0, stream>>>(B2, 512, w3, b_s3, B1, 512, 512, N_PAD);
    gemm_bt<256, 2, true, true, false><<<dim3(MT, 2), 256, 0, stream>>>(B1, 512, w4, b_s4, B2, 512, 512, N_PAD);

    // project h -> 256 (mu|logvar heads) BEFORE aggregation; single col-tile
    __bf16* t = B1;  // N_PAD x 256 bf16
    gemm_bt<256, 0, false, true, false><<<dim3(MT, 1), 256, 0, stream>>>(B2, 512, wml, nullptr, t, 256, 512, N_PAD);

    // second aggregation, fused bias+relu
    __bf16* p = B2;  // N x 256 bf16
    aggt_gather<<<(N_NODES + 3) / 4, 256, 0, stream>>>(t, ptr, col, b_m1, b_l1, p);

    // heads
    float* mu = (float*)d_out;
    float* lv = mu + (size_t)N_NODES * 128;
    gemm_bt<128, 0, true, false, true><<<dim3(MT, 1), 256, 0, stream>>>(p, 256, wm2, b_m2, mu, 128, 128, N_NODES);
    gemm_bt<128, 0, true, false, true><<<dim3(MT, 1), 256, 0, stream>>>(p + 128, 256, wl2, b_l2, lv, 128, 128, N_NODES);
}

// Round 5
// 522.022 us; speedup vs baseline: 1.2640x; 1.2640x over previous
//
#include <hip/hip_runtime.h>
#include <hip/hip_bf16.h>
#include <stdint.h>

#define N_NODES 50000
#define N_PAD   50048   // 391 * 128
#define E_EDGES 800000
#define MT      391     // row tiles of 128

typedef __bf16 bf16x8 __attribute__((ext_vector_type(8)));
typedef __bf16 bf16x4 __attribute__((ext_vector_type(4)));
typedef float  f32x4  __attribute__((ext_vector_type(4)));

// ---------------- CSR build ----------------
__global__ void count_deg(const int* __restrict__ ei, int* __restrict__ cnt) {
    int e = blockIdx.x * blockDim.x + threadIdx.x;
    if (e < E_EDGES) atomicAdd(&cnt[ei[E_EDGES + e]], 1);
}

#define SCAN_B 1024
__global__ void scan_block(const int* __restrict__ cnt, int* __restrict__ ptr,
                           int* __restrict__ bsum, int n) {
    __shared__ int buf[SCAN_B];
    int i = blockIdx.x * SCAN_B + threadIdx.x;
    int v = (i < n) ? cnt[i] : 0;
    buf[threadIdx.x] = v;
    __syncthreads();
    #pragma unroll
    for (int off = 1; off < SCAN_B; off <<= 1) {
        int t = (threadIdx.x >= (unsigned)off) ? buf[threadIdx.x - off] : 0;
        __syncthreads();
        buf[threadIdx.x] += t;
        __syncthreads();
    }
    if (i < n) ptr[i] = buf[threadIdx.x] - v;
    if (threadIdx.x == SCAN_B - 1) bsum[blockIdx.x] = buf[SCAN_B - 1];
}

__global__ void scan_bsums(int* __restrict__ bsum, int* __restrict__ boff, int nb,
                           int* __restrict__ total_out) {
    __shared__ int buf[64];
    int v = ((int)threadIdx.x < nb) ? bsum[threadIdx.x] : 0;
    buf[threadIdx.x] = v;
    __syncthreads();
    #pragma unroll
    for (int off = 1; off < 64; off <<= 1) {
        int t = (threadIdx.x >= (unsigned)off) ? buf[threadIdx.x - off] : 0;
        __syncthreads();
        buf[threadIdx.x] += t;
        __syncthreads();
    }
    if ((int)threadIdx.x < nb) boff[threadIdx.x] = buf[threadIdx.x] - v;
    if (threadIdx.x == 63) *total_out = buf[63];
}

__global__ void scan_add(int* __restrict__ ptr, const int* __restrict__ boff, int n) {
    int i = blockIdx.x * SCAN_B + threadIdx.x;
    if (i < n) ptr[i] += boff[blockIdx.x];
}

__global__ void fill_csr(const int* __restrict__ ei, const int* __restrict__ ptr,
                         int* __restrict__ cursor, int* __restrict__ col) {
    int e = blockIdx.x * blockDim.x + threadIdx.x;
    if (e < E_EDGES) {
        int dst = ei[E_EDGES + e];
        int pos = ptr[dst] + atomicAdd(&cursor[dst], 1);
        col[pos] = ei[e];
    }
}

// ---------------- one-shot fp32 -> bf16 conversion (x + all weights) -----------
#define XN      3200000
#define WTOT    983040
__global__ void cvt_all(const float* __restrict__ x,
                        const float* __restrict__ Ws1, const float* __restrict__ Ws2,
                        const float* __restrict__ Ws3, const float* __restrict__ Ws4,
                        const float* __restrict__ Wm1, const float* __restrict__ Wl1,
                        const float* __restrict__ Wm2, const float* __restrict__ Wl2,
                        __bf16* __restrict__ xb, __bf16* __restrict__ wbuf) {
    int i = blockIdx.x * blockDim.x + threadIdx.x;
    if (i < XN) { xb[i] = (__bf16)x[i]; return; }
    int j = i - XN;
    if (j >= WTOT) return;
    const float* s; int o;
    if      (j <  32768) { s = Ws1; o = j; }
    else if (j < 294912) { s = Ws2; o = j -  32768; }
    else if (j < 557056) { s = Ws3; o = j - 294912; }
    else if (j < 819200) { s = Ws4; o = j - 557056; }
    else if (j < 884736) { s = Wm1; o = j - 819200; }
    else if (j < 950272) { s = Wl1; o = j - 884736; }
    else if (j < 966656) { s = Wm2; o = j - 950272; }
    else                 { s = Wl2; o = j - 966656; }
    wbuf[j] = (__bf16)s[o];
}

// ---------------- aggregation (gather over CSR, fp32 accumulate) ---------------
__global__ void agg0_gather(const __bf16* __restrict__ xb, const int* __restrict__ ptr,
                            const int* __restrict__ col, __bf16* __restrict__ out) {
    int node = blockIdx.x * 4 + (threadIdx.x >> 6);
    int lane = threadIdx.x & 63;
    if (node >= N_PAD) return;
    long o = (long)node * 64 + lane;
    if (node >= N_NODES) { out[o] = (__bf16)0.0f; return; }
    float acc = (float)xb[o];
    int e0 = ptr[node], e1 = ptr[node + 1];
    int e = e0;
    for (; e + 8 <= e1; e += 8) {
        int c[8];
        #pragma unroll
        for (int u = 0; u < 8; ++u) c[u] = col[e + u];
        float v[8];
        #pragma unroll
        for (int u = 0; u < 8; ++u) v[u] = (float)xb[(long)c[u] * 64 + lane];
        #pragma unroll
        for (int u = 0; u < 8; ++u) acc += v[u];
    }
    for (; e < e1; ++e) acc += (float)xb[(long)col[e] * 64 + lane];
    out[o] = (__bf16)acc;
}

__global__ void aggt_gather(const __bf16* __restrict__ t, const int* __restrict__ ptr,
                            const int* __restrict__ col, const float* __restrict__ b_m1,
                            const float* __restrict__ b_l1, __bf16* __restrict__ p) {
    int node = blockIdx.x * 4 + (threadIdx.x >> 6);
    int lane = threadIdx.x & 63;
    if (node >= N_NODES) return;
    const int f0 = lane * 4;
    bf16x4 s = *(const bf16x4*)&t[(long)node * 256 + f0];
    float a0 = (float)s[0], a1 = (float)s[1], a2 = (float)s[2], a3 = (float)s[3];
    int e0 = ptr[node], e1 = ptr[node + 1];
    int e = e0;
    for (; e + 8 <= e1; e += 8) {
        int c[8];
        #pragma unroll
        for (int u = 0; u < 8; ++u) c[u] = col[e + u];
        bf16x4 v[8];
        #pragma unroll
        for (int u = 0; u < 8; ++u) v[u] = *(const bf16x4*)&t[(long)c[u] * 256 + f0];
        #pragma unroll
        for (int u = 0; u < 8; ++u) {
            a0 += (float)v[u][0]; a1 += (float)v[u][1];
            a2 += (float)v[u][2]; a3 += (float)v[u][3];
        }
    }
    for (; e < e1; ++e) {
        bf16x4 v = *(const bf16x4*)&t[(long)col[e] * 256 + f0];
        a0 += (float)v[0]; a1 += (float)v[1]; a2 += (float)v[2]; a3 += (float)v[3];
    }
    float b0, b1, b2, b3;
    if (f0 < 128) { b0 = b_m1[f0]; b1 = b_m1[f0+1]; b2 = b_m1[f0+2]; b3 = b_m1[f0+3]; }
    else          { b0 = b_l1[f0-128]; b1 = b_l1[f0-127]; b2 = b_l1[f0-126]; b3 = b_l1[f0-125]; }
    bf16x4 r;
    r[0] = (__bf16)fmaxf(a0 + b0, 0.0f);
    r[1] = (__bf16)fmaxf(a1 + b1, 0.0f);
    r[2] = (__bf16)fmaxf(a2 + b2, 0.0f);
    r[3] = (__bf16)fmaxf(a3 + b3, 0.0f);
    *(bf16x4*)&p[(long)node * 256 + f0] = r;
}

// ---------------- bf16 MFMA GEMM core: C[M,N] = A[M,K]*W[N,K]^T, BK=64 ---------
// Tile 128x128, 4 waves (64x64 each, acc 4x4 = 64 VGPRs). LDS 2x16KB.
// LDS layout: row r (64 k-elems, 8 granules of 8): granule kt stored at slot
// kt ^ (r&7). Staging: 1-KB chunks = 8 rows x 128B; lane l -> row 8c+(l>>3),
// granule (l&7)^(l>>3); LDS dest = chunk base + l*16 (wave-uniform+lane*16).
__device__ __forceinline__ void gl_lds16(const __bf16* g, __bf16* l) {
    __builtin_amdgcn_global_load_lds(
        (const __attribute__((address_space(1))) uint32_t*)g,
        (__attribute__((address_space(3))) uint32_t*)l, 16, 0, 0);
}

template <int ACT, bool BIAS, bool OUT_BF16, bool MCHK>
__device__ __forceinline__ void gemm_core(
    const __bf16* __restrict__ A, int lda, const __bf16* __restrict__ W,
    const float* __restrict__ bias, void* __restrict__ Cout, int ldc,
    int K, long Mstore, long blockRow, int blockCol,
    __bf16* __restrict__ As, __bf16* __restrict__ Ws) {
    const int tid  = threadIdx.x;
    const int wid  = tid >> 6;
    const int lane = tid & 63;
    const int wm = (wid >> 1) << 6;
    const int wn = (wid & 1) << 6;

    f32x4 acc[4][4];
    #pragma unroll
    for (int i = 0; i < 4; ++i)
        #pragma unroll
        for (int j = 0; j < 4; ++j) acc[i][j] = (f32x4)0.0f;

    // staging addresses: wave w owns chunks 4w..4w+3 of As and of Ws
    const int srow = lane >> 3;            // row within 8-row chunk
    const int skg  = (lane & 7) ^ srow;    // true k-granule for swizzled slot
    const __bf16* gA[4]; const __bf16* gW[4];
    __bf16 *lA[4], *lW[4];
    #pragma unroll
    for (int i = 0; i < 4; ++i) {
        int c = wid * 4 + i;
        gA[i] = A + (blockRow + c * 8 + srow) * (long)lda + skg * 8;
        gW[i] = W + ((long)blockCol + c * 8 + srow) * (long)K + skg * 8;
        lA[i] = As + c * 512;
        lW[i] = Ws + c * 512;
    }

    const int rA = lane & 15;
    const int q  = lane >> 4;
    const int r7 = rA & 7;

    for (int k0 = 0; k0 < K; k0 += 64) {
        #pragma unroll
        for (int i = 0; i < 4; ++i) gl_lds16(gA[i] + k0, lA[i]);
        #pragma unroll
        for (int i = 0; i < 4; ++i) gl_lds16(gW[i] + k0, lW[i]);
        __syncthreads();

        #pragma unroll
        for (int s = 0; s < 2; ++s) {
            const int slot = ((s * 4 + q) ^ r7) * 8;
            bf16x8 af[4], bf[4];
            #pragma unroll
            for (int mi = 0; mi < 4; ++mi)
                af[mi] = *(const bf16x8*)&As[(wm + mi * 16 + rA) * 64 + slot];
            #pragma unroll
            for (int ni = 0; ni < 4; ++ni)
                bf[ni] = *(const bf16x8*)&Ws[(wn + ni * 16 + rA) * 64 + slot];
            #pragma unroll
            for (int mi = 0; mi < 4; ++mi)
                #pragma unroll
                for (int ni = 0; ni < 4; ++ni)
                    acc[mi][ni] = __builtin_amdgcn_mfma_f32_16x16x32_bf16(
                        af[mi], bf[ni], acc[mi][ni], 0, 0, 0);
        }
        __syncthreads();
    }

    // epilogue: C/D layout col=lane&15, row=(lane>>4)*4+reg
    const int ccol = lane & 15;
    const int crow = (lane >> 4) << 2;
    #pragma unroll
    for (int mi = 0; mi < 4; ++mi) {
        #pragma unroll
        for (int ni = 0; ni < 4; ++ni) {
            long gr0 = blockRow + wm + mi * 16 + crow;
            int  gc  = blockCol + wn + ni * 16 + ccol;
            float bv = BIAS ? bias[gc] : 0.0f;
            #pragma unroll
            for (int r = 0; r < 4; ++r) {
                long gr = gr0 + r;
                if (!MCHK || gr < Mstore) {
                    float v = acc[mi][ni][r] + bv;
                    if (ACT == 1) v = (v > 0.0f) ? v : 0.1f * v;
                    else if (ACT == 2) v = fmaxf(v, 0.0f);
                    if (OUT_BF16) ((__bf16*)Cout)[gr * ldc + gc] = (__bf16)v;
                    else          ((float*)Cout)[gr * ldc + gc] = v;
                }
            }
        }
    }
}

template <int ACT, bool BIAS, bool OUT_BF16, bool MCHK>
__global__ __launch_bounds__(256) void gemm_bt(
    const __bf16* __restrict__ A, int lda, const __bf16* __restrict__ W,
    const float* __restrict__ bias, void* __restrict__ Cout, int ldc,
    int K, long Mstore) {
    __shared__ __bf16 As[128 * 64];
    __shared__ __bf16 Ws[128 * 64];
    gemm_core<ACT, BIAS, OUT_BF16, MCHK>(A, lda, W, bias, Cout, ldc, K, Mstore,
                                         (long)blockIdx.x * 128, blockIdx.y * 128,
                                         As, Ws);
}

// both heads in one dispatch: blockIdx.y selects mu vs logvar.
// NOTE: K=128 (each head consumes its 128-dim half of p); lda=256 (p row stride).
__global__ __launch_bounds__(256) void gemm_heads(
    const __bf16* __restrict__ p, const __bf16* __restrict__ wm2,
    const float* __restrict__ b_m2, float* __restrict__ mu,
    const __bf16* __restrict__ wl2, const float* __restrict__ b_l2,
    float* __restrict__ lv) {
    __shared__ __bf16 As[128 * 64];
    __shared__ __bf16 Ws[128 * 64];
    if (blockIdx.y == 0)
        gemm_core<0, true, false, true>(p, 256, wm2, b_m2, mu, 128, 128, N_NODES,
                                        (long)blockIdx.x * 128, 0, As, Ws);
    else
        gemm_core<0, true, false, true>(p + 128, 256, wl2, b_l2, lv, 128, 128, N_NODES,
                                        (long)blockIdx.x * 128, 0, As, Ws);
}

extern "C" void kernel_launch(void* const* d_in, const int* in_sizes, int n_in,
                              void* d_out, int out_size, void* d_ws, size_t ws_size,
                              hipStream_t stream) {
    const float* x    = (const float*)d_in[0];
    const int*   ei   = (const int*)d_in[1];
    const float* W_s1 = (const float*)d_in[2];
    const float* b_s1 = (const float*)d_in[3];
    const float* W_s2 = (const float*)d_in[4];
    const float* b_s2 = (const float*)d_in[5];
    const float* W_s3 = (const float*)d_in[6];
    const float* b_s3 = (const float*)d_in[7];
    const float* W_s4 = (const float*)d_in[8];
    const float* b_s4 = (const float*)d_in[9];
    const float* W_m1 = (const float*)d_in[10];
    const float* b_m1 = (const float*)d_in[11];
    const float* W_m2 = (const float*)d_in[12];
    const float* b_m2 = (const float*)d_in[13];
    const float* W_l1 = (const float*)d_in[14];
    const float* b_l1 = (const float*)d_in[15];
    const float* W_l2 = (const float*)d_in[16];
    const float* b_l2 = (const float*)d_in[17];

    char* ws = (char*)d_ws;
    size_t off = 0;
    auto carve = [&](size_t bytes) -> void* {
        void* p = ws + off;
        off = (off + bytes + 255) & ~(size_t)255;
        return p;
    };
    int* cnt  = (int*)carve((size_t)N_NODES * 4);
    int* cur  = (int*)carve((size_t)N_NODES * 4);
    int* ptr  = (int*)carve((size_t)(N_NODES + 1) * 4);
    int* col  = (int*)carve((size_t)E_EDGES * 4);
    int* bsum = (int*)carve(64 * 4);
    int* boff = (int*)carve(64 * 4);
    __bf16* wbuf = (__bf16*)carve((size_t)WTOT * 2);
    __bf16* w1  = wbuf;
    __bf16* w2  = wbuf +  32768;
    __bf16* w3  = wbuf + 294912;
    __bf16* w4  = wbuf + 557056;
    __bf16* wml = wbuf + 819200;   // [W_m1 ; W_l1] rows, 256x512
    __bf16* wm2 = wbuf + 950272;
    __bf16* wl2 = wbuf + 966656;
    __bf16* xb    = (__bf16*)carve((size_t)XN * 2);
    __bf16* agg0b = (__bf16*)carve((size_t)N_PAD * 64 * 2);
    __bf16* B1    = (__bf16*)carve((size_t)N_PAD * 512 * 2);
    __bf16* B2    = (__bf16*)carve((size_t)N_PAD * 512 * 2);

    (void)hipMemsetAsync(cnt, 0, (size_t)N_NODES * 4, stream);
    (void)hipMemsetAsync(cur, 0, (size_t)N_NODES * 4, stream);

    // CSR build
    const int NB = (N_NODES + SCAN_B - 1) / SCAN_B;  // 49
    count_deg<<<E_EDGES / 256, 256, 0, stream>>>(ei, cnt);
    scan_block<<<NB, SCAN_B, 0, stream>>>(cnt, ptr, bsum, N_NODES);
    scan_bsums<<<1, 64, 0, stream>>>(bsum, boff, NB, &ptr[N_NODES]);
    scan_add<<<NB, SCAN_B, 0, stream>>>(ptr, boff, N_NODES);
    fill_csr<<<E_EDGES / 256, 256, 0, stream>>>(ei, ptr, cur, col);

    // one-shot conversions
    cvt_all<<<(XN + WTOT + 255) / 256, 256, 0, stream>>>(
        x, W_s1, W_s2, W_s3, W_s4, W_m1, W_l1, W_m2, W_l2, xb, wbuf);

    // first aggregation
    agg0_gather<<<N_PAD / 4, 256, 0, stream>>>(xb, ptr, col, agg0b);

    // shared MLP: 64->512->512->512->512, lrelu x3, final +b then relu
    gemm_bt<1, true, true, false><<<dim3(MT, 4), 256, 0, stream>>>(agg0b, 64, w1, b_s1, B1, 512, 64, N_PAD);
    gemm_bt<1, true, true, false><<<dim3(MT, 4), 256, 0, stream>>>(B1, 512, w2, b_s2, B2, 512, 512, N_PAD);
    gemm_bt<1, true, true, false><<<dim3(MT, 4), 256, 0, stream>>>(B2, 512, w3, b_s3, B1, 512, 512, N_PAD);
    gemm_bt<2, true, true, false><<<dim3(MT, 4), 256, 0, stream>>>(B1, 512, w4, b_s4, B2, 512, 512, N_PAD);

    // project h -> 256 (mu|logvar heads) BEFORE aggregation; bf16 out
    __bf16* t = B1;  // N_PAD x 256 bf16
    gemm_bt<0, false, true, false><<<dim3(MT, 2), 256, 0, stream>>>(B2, 512, wml, nullptr, t, 256, 512, N_PAD);

    // second aggregation, fused bias+relu
    __bf16* p = B2;  // N x 256 bf16
    aggt_gather<<<(N_NODES + 3) / 4, 256, 0, stream>>>(t, ptr, col, b_m1, b_l1, p);

    // heads (one dispatch, blockIdx.y = head)
    float* mu = (float*)d_out;
    float* lv = mu + (size_t)N_NODES * 128;
    gemm_heads<<<dim3(MT, 2), 256, 0, stream>>>(p, wm2, b_m2, mu, wl2, b_l2, lv);
}

// Round 6
// 500.304 us; speedup vs baseline: 1.3189x; 1.0434x over previous
//
#include <hip/hip_runtime.h>
#include <hip/hip_bf16.h>
#include <stdint.h>

#define N_NODES 50000
#define N_PAD   50048   // 391 * 128
#define E_EDGES 800000
#define MT      391     // row tiles of 128

typedef __bf16 bf16x8 __attribute__((ext_vector_type(8)));
typedef __bf16 bf16x4 __attribute__((ext_vector_type(4)));
typedef float  f32x4  __attribute__((ext_vector_type(4)));

// ---------------- CSR build ----------------
__global__ void count_deg(const int* __restrict__ ei, int* __restrict__ cnt) {
    int e = blockIdx.x * blockDim.x + threadIdx.x;
    if (e < E_EDGES) atomicAdd(&cnt[ei[E_EDGES + e]], 1);
}

#define SCAN_B 1024
__global__ void scan_block(const int* __restrict__ cnt, int* __restrict__ ptr,
                           int* __restrict__ bsum, int n) {
    __shared__ int buf[SCAN_B];
    int i = blockIdx.x * SCAN_B + threadIdx.x;
    int v = (i < n) ? cnt[i] : 0;
    buf[threadIdx.x] = v;
    __syncthreads();
    #pragma unroll
    for (int off = 1; off < SCAN_B; off <<= 1) {
        int t = (threadIdx.x >= (unsigned)off) ? buf[threadIdx.x - off] : 0;
        __syncthreads();
        buf[threadIdx.x] += t;
        __syncthreads();
    }
    if (i < n) ptr[i] = buf[threadIdx.x] - v;
    if (threadIdx.x == SCAN_B - 1) bsum[blockIdx.x] = buf[SCAN_B - 1];
}

__global__ void scan_bsums(int* __restrict__ bsum, int* __restrict__ boff, int nb,
                           int* __restrict__ total_out) {
    __shared__ int buf[64];
    int v = ((int)threadIdx.x < nb) ? bsum[threadIdx.x] : 0;
    buf[threadIdx.x] = v;
    __syncthreads();
    #pragma unroll
    for (int off = 1; off < 64; off <<= 1) {
        int t = (threadIdx.x >= (unsigned)off) ? buf[threadIdx.x - off] : 0;
        __syncthreads();
        buf[threadIdx.x] += t;
        __syncthreads();
    }
    if ((int)threadIdx.x < nb) boff[threadIdx.x] = buf[threadIdx.x] - v;
    if (threadIdx.x == 63) *total_out = buf[63];
}

__global__ void scan_add(int* __restrict__ ptr, const int* __restrict__ boff, int n) {
    int i = blockIdx.x * SCAN_B + threadIdx.x;
    if (i < n) ptr[i] += boff[blockIdx.x];
}

__global__ void fill_csr(const int* __restrict__ ei, const int* __restrict__ ptr,
                         int* __restrict__ cursor, int* __restrict__ col) {
    int e = blockIdx.x * blockDim.x + threadIdx.x;
    if (e < E_EDGES) {
        int dst = ei[E_EDGES + e];
        int pos = ptr[dst] + atomicAdd(&cursor[dst], 1);
        col[pos] = ei[e];
    }
}

// ---------------- one-shot fp32 -> bf16 conversion (x + all weights) -----------
#define XN      3200000
#define WTOT    983040
__global__ void cvt_all(const float* __restrict__ x,
                        const float* __restrict__ Ws1, const float* __restrict__ Ws2,
                        const float* __restrict__ Ws3, const float* __restrict__ Ws4,
                        const float* __restrict__ Wm1, const float* __restrict__ Wl1,
                        const float* __restrict__ Wm2, const float* __restrict__ Wl2,
                        __bf16* __restrict__ xb, __bf16* __restrict__ wbuf) {
    int i = blockIdx.x * blockDim.x + threadIdx.x;
    if (i < XN) { xb[i] = (__bf16)x[i]; return; }
    int j = i - XN;
    if (j >= WTOT) return;
    const float* s; int o;
    if      (j <  32768) { s = Ws1; o = j; }
    else if (j < 294912) { s = Ws2; o = j -  32768; }
    else if (j < 557056) { s = Ws3; o = j - 294912; }
    else if (j < 819200) { s = Ws4; o = j - 557056; }
    else if (j < 884736) { s = Wm1; o = j - 819200; }
    else if (j < 950272) { s = Wl1; o = j - 884736; }
    else if (j < 966656) { s = Wm2; o = j - 950272; }
    else                 { s = Wl2; o = j - 966656; }
    wbuf[j] = (__bf16)s[o];
}

// ---------------- aggregation (gather over CSR, fp32 accumulate) ---------------
__global__ void agg0_gather(const __bf16* __restrict__ xb, const int* __restrict__ ptr,
                            const int* __restrict__ col, __bf16* __restrict__ out) {
    int node = blockIdx.x * 4 + (threadIdx.x >> 6);
    int lane = threadIdx.x & 63;
    if (node >= N_PAD) return;
    long o = (long)node * 64 + lane;
    if (node >= N_NODES) { out[o] = (__bf16)0.0f; return; }
    float acc = (float)xb[o];
    int e0 = ptr[node], e1 = ptr[node + 1];
    int e = e0;
    for (; e + 8 <= e1; e += 8) {
        int c[8];
        #pragma unroll
        for (int u = 0; u < 8; ++u) c[u] = col[e + u];
        float v[8];
        #pragma unroll
        for (int u = 0; u < 8; ++u) v[u] = (float)xb[(long)c[u] * 64 + lane];
        #pragma unroll
        for (int u = 0; u < 8; ++u) acc += v[u];
    }
    for (; e < e1; ++e) acc += (float)xb[(long)col[e] * 64 + lane];
    out[o] = (__bf16)acc;
}

__global__ void aggt_gather(const __bf16* __restrict__ t, const int* __restrict__ ptr,
                            const int* __restrict__ col, const float* __restrict__ b_m1,
                            const float* __restrict__ b_l1, __bf16* __restrict__ p) {
    int node = blockIdx.x * 4 + (threadIdx.x >> 6);
    int lane = threadIdx.x & 63;
    if (node >= N_NODES) return;
    const int f0 = lane * 4;
    bf16x4 s = *(const bf16x4*)&t[(long)node * 256 + f0];
    float a0 = (float)s[0], a1 = (float)s[1], a2 = (float)s[2], a3 = (float)s[3];
    int e0 = ptr[node], e1 = ptr[node + 1];
    int e = e0;
    for (; e + 16 <= e1; e += 16) {             // 16 independent 8-B loads in flight
        int c[16];
        #pragma unroll
        for (int u = 0; u < 16; ++u) c[u] = col[e + u];
        bf16x4 v[16];
        #pragma unroll
        for (int u = 0; u < 16; ++u) v[u] = *(const bf16x4*)&t[(long)c[u] * 256 + f0];
        #pragma unroll
        for (int u = 0; u < 16; ++u) {
            a0 += (float)v[u][0]; a1 += (float)v[u][1];
            a2 += (float)v[u][2]; a3 += (float)v[u][3];
        }
    }
    for (; e + 4 <= e1; e += 4) {
        int c[4];
        #pragma unroll
        for (int u = 0; u < 4; ++u) c[u] = col[e + u];
        bf16x4 v[4];
        #pragma unroll
        for (int u = 0; u < 4; ++u) v[u] = *(const bf16x4*)&t[(long)c[u] * 256 + f0];
        #pragma unroll
        for (int u = 0; u < 4; ++u) {
            a0 += (float)v[u][0]; a1 += (float)v[u][1];
            a2 += (float)v[u][2]; a3 += (float)v[u][3];
        }
    }
    for (; e < e1; ++e) {
        bf16x4 v = *(const bf16x4*)&t[(long)col[e] * 256 + f0];
        a0 += (float)v[0]; a1 += (float)v[1]; a2 += (float)v[2]; a3 += (float)v[3];
    }
    float b0, b1, b2, b3;
    if (f0 < 128) { b0 = b_m1[f0]; b1 = b_m1[f0+1]; b2 = b_m1[f0+2]; b3 = b_m1[f0+3]; }
    else          { b0 = b_l1[f0-128]; b1 = b_l1[f0-127]; b2 = b_l1[f0-126]; b3 = b_l1[f0-125]; }
    bf16x4 r;
    r[0] = (__bf16)fmaxf(a0 + b0, 0.0f);
    r[1] = (__bf16)fmaxf(a1 + b1, 0.0f);
    r[2] = (__bf16)fmaxf(a2 + b2, 0.0f);
    r[3] = (__bf16)fmaxf(a3 + b3, 0.0f);
    *(bf16x4*)&p[(long)node * 256 + f0] = r;
}

// ---------------- bf16 MFMA GEMM core: C[M,N] = A[M,K]*W[N,K]^T, BK=64 ---------
// Tile 128x128, 4 waves (64x64 each, acc 4x4 = 64 VGPRs). LDS 2x16KB.
// LDS layout: row r (64 k-elems, 8 granules of 8): granule kt stored at slot
// kt ^ (r&7). Staging: 1-KB chunks = 8 rows x 128B; lane l -> row 8c+(l>>3),
// granule (l&7)^(l>>3); LDS dest = chunk base + l*16 (wave-uniform+lane*16).
__device__ __forceinline__ void gl_lds16(const __bf16* g, __bf16* l) {
    __builtin_amdgcn_global_load_lds(
        (const __attribute__((address_space(1))) uint32_t*)g,
        (__attribute__((address_space(3))) uint32_t*)l, 16, 0, 0);
}

// XCD-aware swizzle: linear block ids round-robin XCDs (id%8). Map
// bid -> (x,y) so the NCOL y-tiles of one x-strip share an XCD (ids differ
// by `width`=8 within one group) and run back-to-back: the 131-KB A-strip is
// fetched beyond-L2 once per x instead of NCOL times.
template <int NCOL>
__device__ __forceinline__ void swizzle_xy(int bid, int& x, int& y) {
    int grp  = bid / (8 * NCOL);
    int rem  = bid - grp * (8 * NCOL);
    int base = grp * 8;
    int width = MT - base; if (width > 8) width = 8;
    x = base + rem % width;
    y = rem / width;
}

template <int ACT, bool BIAS, bool OUT_BF16, bool MCHK>
__device__ __forceinline__ void gemm_core(
    const __bf16* __restrict__ A, int lda, const __bf16* __restrict__ W,
    const float* __restrict__ bias, void* __restrict__ Cout, int ldc,
    int K, long Mstore, long blockRow, int blockCol,
    __bf16* __restrict__ As, __bf16* __restrict__ Ws) {
    const int tid  = threadIdx.x;
    const int wid  = tid >> 6;
    const int lane = tid & 63;
    const int wm = (wid >> 1) << 6;
    const int wn = (wid & 1) << 6;

    f32x4 acc[4][4];
    #pragma unroll
    for (int i = 0; i < 4; ++i)
        #pragma unroll
        for (int j = 0; j < 4; ++j) acc[i][j] = (f32x4)0.0f;

    // staging addresses: wave w owns chunks 4w..4w+3 of As and of Ws
    const int srow = lane >> 3;            // row within 8-row chunk
    const int skg  = (lane & 7) ^ srow;    // true k-granule for swizzled slot
    const __bf16* gA[4]; const __bf16* gW[4];
    __bf16 *lA[4], *lW[4];
    #pragma unroll
    for (int i = 0; i < 4; ++i) {
        int c = wid * 4 + i;
        gA[i] = A + (blockRow + c * 8 + srow) * (long)lda + skg * 8;
        gW[i] = W + ((long)blockCol + c * 8 + srow) * (long)K + skg * 8;
        lA[i] = As + c * 512;
        lW[i] = Ws + c * 512;
    }

    const int rA = lane & 15;
    const int q  = lane >> 4;
    const int r7 = rA & 7;

    for (int k0 = 0; k0 < K; k0 += 64) {
        #pragma unroll
        for (int i = 0; i < 4; ++i) gl_lds16(gA[i] + k0, lA[i]);
        #pragma unroll
        for (int i = 0; i < 4; ++i) gl_lds16(gW[i] + k0, lW[i]);
        __syncthreads();

        #pragma unroll
        for (int s = 0; s < 2; ++s) {
            const int slot = ((s * 4 + q) ^ r7) * 8;
            bf16x8 af[4], bf[4];
            #pragma unroll
            for (int mi = 0; mi < 4; ++mi)
                af[mi] = *(const bf16x8*)&As[(wm + mi * 16 + rA) * 64 + slot];
            #pragma unroll
            for (int ni = 0; ni < 4; ++ni)
                bf[ni] = *(const bf16x8*)&Ws[(wn + ni * 16 + rA) * 64 + slot];
            #pragma unroll
            for (int mi = 0; mi < 4; ++mi)
                #pragma unroll
                for (int ni = 0; ni < 4; ++ni)
                    acc[mi][ni] = __builtin_amdgcn_mfma_f32_16x16x32_bf16(
                        af[mi], bf[ni], acc[mi][ni], 0, 0, 0);
        }
        __syncthreads();
    }

    // epilogue: C/D layout col=lane&15, row=(lane>>4)*4+reg
    const int ccol = lane & 15;
    const int crow = (lane >> 4) << 2;
    #pragma unroll
    for (int mi = 0; mi < 4; ++mi) {
        #pragma unroll
        for (int ni = 0; ni < 4; ++ni) {
            long gr0 = blockRow + wm + mi * 16 + crow;
            int  gc  = blockCol + wn + ni * 16 + ccol;
            float bv = BIAS ? bias[gc] : 0.0f;
            #pragma unroll
            for (int r = 0; r < 4; ++r) {
                long gr = gr0 + r;
                if (!MCHK || gr < Mstore) {
                    float v = acc[mi][ni][r] + bv;
                    if (ACT == 1) v = (v > 0.0f) ? v : 0.1f * v;
                    else if (ACT == 2) v = fmaxf(v, 0.0f);
                    if (OUT_BF16) ((__bf16*)Cout)[gr * ldc + gc] = (__bf16)v;
                    else          ((float*)Cout)[gr * ldc + gc] = v;
                }
            }
        }
    }
}

template <int NCOL, int ACT, bool BIAS, bool OUT_BF16, bool MCHK>
__global__ __launch_bounds__(256) void gemm_bt(
    const __bf16* __restrict__ A, int lda, const __bf16* __restrict__ W,
    const float* __restrict__ bias, void* __restrict__ Cout, int ldc,
    int K, long Mstore) {
    __shared__ __bf16 As[128 * 64];
    __shared__ __bf16 Ws[128 * 64];
    int x, y;
    swizzle_xy<NCOL>(blockIdx.x, x, y);
    gemm_core<ACT, BIAS, OUT_BF16, MCHK>(A, lda, W, bias, Cout, ldc, K, Mstore,
                                         (long)x * 128, y * 128, As, Ws);
}

// both heads in one 1D dispatch; swizzled so both heads of one p-strip share
// an XCD (p-strip fetched once). K=128 (each head uses its half), lda=256.
__global__ __launch_bounds__(256) void gemm_heads(
    const __bf16* __restrict__ p, const __bf16* __restrict__ wm2,
    const float* __restrict__ b_m2, float* __restrict__ mu,
    const __bf16* __restrict__ wl2, const float* __restrict__ b_l2,
    float* __restrict__ lv) {
    __shared__ __bf16 As[128 * 64];
    __shared__ __bf16 Ws[128 * 64];
    int x, hd;
    swizzle_xy<2>(blockIdx.x, x, hd);
    if (hd == 0)
        gemm_core<0, true, false, true>(p, 256, wm2, b_m2, mu, 128, 128, N_NODES,
                                        (long)x * 128, 0, As, Ws);
    else
        gemm_core<0, true, false, true>(p + 128, 256, wl2, b_l2, lv, 128, 128, N_NODES,
                                        (long)x * 128, 0, As, Ws);
}

extern "C" void kernel_launch(void* const* d_in, const int* in_sizes, int n_in,
                              void* d_out, int out_size, void* d_ws, size_t ws_size,
                              hipStream_t stream) {
    const float* x    = (const float*)d_in[0];
    const int*   ei   = (const int*)d_in[1];
    const float* W_s1 = (const float*)d_in[2];
    const float* b_s1 = (const float*)d_in[3];
    const float* W_s2 = (const float*)d_in[4];
    const float* b_s2 = (const float*)d_in[5];
    const float* W_s3 = (const float*)d_in[6];
    const float* b_s3 = (const float*)d_in[7];
    const float* W_s4 = (const float*)d_in[8];
    const float* b_s4 = (const float*)d_in[9];
    const float* W_m1 = (const float*)d_in[10];
    const float* b_m1 = (const float*)d_in[11];
    const float* W_m2 = (const float*)d_in[12];
    const float* b_m2 = (const float*)d_in[13];
    const float* W_l1 = (const float*)d_in[14];
    const float* b_l1 = (const float*)d_in[15];
    const float* W_l2 = (const float*)d_in[16];
    const float* b_l2 = (const float*)d_in[17];

    char* ws = (char*)d_ws;
    size_t off = 0;
    auto carve = [&](size_t bytes) -> void* {
        void* p = ws + off;
        off = (off + bytes + 255) & ~(size_t)255;
        return p;
    };
    int* cnt  = (int*)carve((size_t)N_NODES * 4);
    int* cur  = (int*)carve((size_t)N_NODES * 4);
    int* ptr  = (int*)carve((size_t)(N_NODES + 1) * 4);
    int* col  = (int*)carve((size_t)E_EDGES * 4);
    int* bsum = (int*)carve(64 * 4);
    int* boff = (int*)carve(64 * 4);
    __bf16* wbuf = (__bf16*)carve((size_t)WTOT * 2);
    __bf16* w1  = wbuf;
    __bf16* w2  = wbuf +  32768;
    __bf16* w3  = wbuf + 294912;
    __bf16* w4  = wbuf + 557056;
    __bf16* wml = wbuf + 819200;   // [W_m1 ; W_l1] rows, 256x512
    __bf16* wm2 = wbuf + 950272;
    __bf16* wl2 = wbuf + 966656;
    __bf16* xb    = (__bf16*)carve((size_t)XN * 2);
    __bf16* agg0b = (__bf16*)carve((size_t)N_PAD * 64 * 2);
    __bf16* B1    = (__bf16*)carve((size_t)N_PAD * 512 * 2);
    __bf16* B2    = (__bf16*)carve((size_t)N_PAD * 512 * 2);

    (void)hipMemsetAsync(cnt, 0, (size_t)N_NODES * 4, stream);
    (void)hipMemsetAsync(cur, 0, (size_t)N_NODES * 4, stream);

    // CSR build
    const int NB = (N_NODES + SCAN_B - 1) / SCAN_B;  // 49
    count_deg<<<E_EDGES / 256, 256, 0, stream>>>(ei, cnt);
    scan_block<<<NB, SCAN_B, 0, stream>>>(cnt, ptr, bsum, N_NODES);
    scan_bsums<<<1, 64, 0, stream>>>(bsum, boff, NB, &ptr[N_NODES]);
    scan_add<<<NB, SCAN_B, 0, stream>>>(ptr, boff, N_NODES);
    fill_csr<<<E_EDGES / 256, 256, 0, stream>>>(ei, ptr, cur, col);

    // one-shot conversions
    cvt_all<<<(XN + WTOT + 255) / 256, 256, 0, stream>>>(
        x, W_s1, W_s2, W_s3, W_s4, W_m1, W_l1, W_m2, W_l2, xb, wbuf);

    // first aggregation
    agg0_gather<<<N_PAD / 4, 256, 0, stream>>>(xb, ptr, col, agg0b);

    // shared MLP: 64->512->512->512->512, lrelu x3, final +b then relu
    gemm_bt<4, 1, true, true, false><<<MT * 4, 256, 0, stream>>>(agg0b, 64, w1, b_s1, B1, 512, 64, N_PAD);
    gemm_bt<4, 1, true, true, false><<<MT * 4, 256, 0, stream>>>(B1, 512, w2, b_s2, B2, 512, 512, N_PAD);
    gemm_bt<4, 1, true, true, false><<<MT * 4, 256, 0, stream>>>(B2, 512, w3, b_s3, B1, 512, 512, N_PAD);
    gemm_bt<4, 2, true, true, false><<<MT * 4, 256, 0, stream>>>(B1, 512, w4, b_s4, B2, 512, 512, N_PAD);

    // project h -> 256 (mu|logvar heads) BEFORE aggregation; bf16 out
    __bf16* t = B1;  // N_PAD x 256 bf16
    gemm_bt<2, 0, false, true, false><<<MT * 2, 256, 0, stream>>>(B2, 512, wml, nullptr, t, 256, 512, N_PAD);

    // second aggregation, fused bias+relu
    __bf16* p = B2;  // N x 256 bf16
    aggt_gather<<<(N_NODES + 3) / 4, 256, 0, stream>>>(t, ptr, col, b_m1, b_l1, p);

    // heads (one swizzled 1D dispatch)
    float* mu = (float*)d_out;
    float* lv = mu + (size_t)N_NODES * 128;
    gemm_heads<<<MT * 2, 256, 0, stream>>>(p, wm2, b_m2, mu, wl2, b_l2, lv);
}

// Round 7
// 498.011 us; speedup vs baseline: 1.3250x; 1.0046x over previous
//
#include <hip/hip_runtime.h>
#include <hip/hip_bf16.h>
#include <stdint.h>

#define N_NODES 50000
#define N_PAD   50048   // 391 * 128
#define E_EDGES 800000
#define MT      391     // row tiles of 128

typedef __bf16 bf16x8 __attribute__((ext_vector_type(8)));
typedef __bf16 bf16x4 __attribute__((ext_vector_type(4)));
typedef float  f32x4  __attribute__((ext_vector_type(4)));

// ---------------- CSR build ----------------
__global__ void count_deg(const int* __restrict__ ei, int* __restrict__ cnt) {
    int e = blockIdx.x * blockDim.x + threadIdx.x;
    if (e < E_EDGES) atomicAdd(&cnt[ei[E_EDGES + e]], 1);
}

#define SCAN_B 1024
__global__ void scan_block(const int* __restrict__ cnt, int* __restrict__ ptr,
                           int* __restrict__ bsum, int n) {
    __shared__ int buf[SCAN_B];
    int i = blockIdx.x * SCAN_B + threadIdx.x;
    int v = (i < n) ? cnt[i] : 0;
    buf[threadIdx.x] = v;
    __syncthreads();
    #pragma unroll
    for (int off = 1; off < SCAN_B; off <<= 1) {
        int t = (threadIdx.x >= (unsigned)off) ? buf[threadIdx.x - off] : 0;
        __syncthreads();
        buf[threadIdx.x] += t;
        __syncthreads();
    }
    if (i < n) ptr[i] = buf[threadIdx.x] - v;
    if (threadIdx.x == SCAN_B - 1) bsum[blockIdx.x] = buf[SCAN_B - 1];
}

__global__ void scan_bsums(int* __restrict__ bsum, int* __restrict__ boff, int nb,
                           int* __restrict__ total_out) {
    __shared__ int buf[64];
    int v = ((int)threadIdx.x < nb) ? bsum[threadIdx.x] : 0;
    buf[threadIdx.x] = v;
    __syncthreads();
    #pragma unroll
    for (int off = 1; off < 64; off <<= 1) {
        int t = (threadIdx.x >= (unsigned)off) ? buf[threadIdx.x - off] : 0;
        __syncthreads();
        buf[threadIdx.x] += t;
        __syncthreads();
    }
    if ((int)threadIdx.x < nb) boff[threadIdx.x] = buf[threadIdx.x] - v;
    if (threadIdx.x == 63) *total_out = buf[63];
}

__global__ void scan_add(int* __restrict__ ptr, const int* __restrict__ boff, int n) {
    int i = blockIdx.x * SCAN_B + threadIdx.x;
    if (i < n) ptr[i] += boff[blockIdx.x];
}

__global__ void fill_csr(const int* __restrict__ ei, const int* __restrict__ ptr,
                         int* __restrict__ cursor, int* __restrict__ col) {
    int e = blockIdx.x * blockDim.x + threadIdx.x;
    if (e < E_EDGES) {
        int dst = ei[E_EDGES + e];
        int pos = ptr[dst] + atomicAdd(&cursor[dst], 1);
        col[pos] = ei[e];
    }
}

// ---------------- one-shot fp32 -> bf16 conversion (x + all weights) -----------
#define XN      3200000
#define WTOT    983040
__global__ void cvt_all(const float* __restrict__ x,
                        const float* __restrict__ Ws1, const float* __restrict__ Ws2,
                        const float* __restrict__ Ws3, const float* __restrict__ Ws4,
                        const float* __restrict__ Wm1, const float* __restrict__ Wl1,
                        const float* __restrict__ Wm2, const float* __restrict__ Wl2,
                        __bf16* __restrict__ xb, __bf16* __restrict__ wbuf) {
    int i = blockIdx.x * blockDim.x + threadIdx.x;
    if (i < XN) { xb[i] = (__bf16)x[i]; return; }
    int j = i - XN;
    if (j >= WTOT) return;
    const float* s; int o;
    if      (j <  32768) { s = Ws1; o = j; }
    else if (j < 294912) { s = Ws2; o = j -  32768; }
    else if (j < 557056) { s = Ws3; o = j - 294912; }
    else if (j < 819200) { s = Ws4; o = j - 557056; }
    else if (j < 884736) { s = Wm1; o = j - 819200; }
    else if (j < 950272) { s = Wl1; o = j - 884736; }
    else if (j < 966656) { s = Wm2; o = j - 950272; }
    else                 { s = Wl2; o = j - 966656; }
    wbuf[j] = (__bf16)s[o];
}

// ---------------- aggregation (gather over CSR, fp32 accumulate) ---------------
__global__ void agg0_gather(const __bf16* __restrict__ xb, const int* __restrict__ ptr,
                            const int* __restrict__ col, __bf16* __restrict__ out) {
    int node = blockIdx.x * 4 + (threadIdx.x >> 6);
    int lane = threadIdx.x & 63;
    if (node >= N_PAD) return;
    long o = (long)node * 64 + lane;
    if (node >= N_NODES) { out[o] = (__bf16)0.0f; return; }
    float acc = (float)xb[o];
    int e0 = ptr[node], e1 = ptr[node + 1];
    int e = e0;
    for (; e + 8 <= e1; e += 8) {
        int c[8];
        #pragma unroll
        for (int u = 0; u < 8; ++u) c[u] = col[e + u];
        float v[8];
        #pragma unroll
        for (int u = 0; u < 8; ++u) v[u] = (float)xb[(long)c[u] * 64 + lane];
        #pragma unroll
        for (int u = 0; u < 8; ++u) acc += v[u];
    }
    for (; e < e1; ++e) acc += (float)xb[(long)col[e] * 64 + lane];
    out[o] = (__bf16)acc;
}

// unroll 8, low VGPR (28) -> occupancy 66%: TLP beats per-wave ILP here (r6 lesson)
__global__ void aggt_gather(const __bf16* __restrict__ t, const int* __restrict__ ptr,
                            const int* __restrict__ col, const float* __restrict__ b_m1,
                            const float* __restrict__ b_l1, __bf16* __restrict__ p) {
    int node = blockIdx.x * 4 + (threadIdx.x >> 6);
    int lane = threadIdx.x & 63;
    if (node >= N_NODES) return;
    const int f0 = lane * 4;
    bf16x4 s = *(const bf16x4*)&t[(long)node * 256 + f0];
    float a0 = (float)s[0], a1 = (float)s[1], a2 = (float)s[2], a3 = (float)s[3];
    int e0 = ptr[node], e1 = ptr[node + 1];
    int e = e0;
    for (; e + 8 <= e1; e += 8) {
        int c[8];
        #pragma unroll
        for (int u = 0; u < 8; ++u) c[u] = col[e + u];
        bf16x4 v[8];
        #pragma unroll
        for (int u = 0; u < 8; ++u) v[u] = *(const bf16x4*)&t[(long)c[u] * 256 + f0];
        #pragma unroll
        for (int u = 0; u < 8; ++u) {
            a0 += (float)v[u][0]; a1 += (float)v[u][1];
            a2 += (float)v[u][2]; a3 += (float)v[u][3];
        }
    }
    for (; e < e1; ++e) {
        bf16x4 v = *(const bf16x4*)&t[(long)col[e] * 256 + f0];
        a0 += (float)v[0]; a1 += (float)v[1]; a2 += (float)v[2]; a3 += (float)v[3];
    }
    float b0, b1, b2, b3;
    if (f0 < 128) { b0 = b_m1[f0]; b1 = b_m1[f0+1]; b2 = b_m1[f0+2]; b3 = b_m1[f0+3]; }
    else          { b0 = b_l1[f0-128]; b1 = b_l1[f0-127]; b2 = b_l1[f0-126]; b3 = b_l1[f0-125]; }
    bf16x4 r;
    r[0] = (__bf16)fmaxf(a0 + b0, 0.0f);
    r[1] = (__bf16)fmaxf(a1 + b1, 0.0f);
    r[2] = (__bf16)fmaxf(a2 + b2, 0.0f);
    r[3] = (__bf16)fmaxf(a3 + b3, 0.0f);
    *(bf16x4*)&p[(long)node * 256 + f0] = r;
}

// ---------------- bf16 MFMA GEMM core: C[M,N] = A[M,K]*W[N,K]^T, BK=64 ---------
// Tile 128x128, 4 waves (64x64 each, acc 4x4 = 64 VGPRs). LDS 32 KB (As|Ws).
// LDS layout: row r (64 k-elems, 8 granules of 8): granule kt at slot kt^(r&7).
__device__ __forceinline__ void gl_lds16(const __bf16* g, __bf16* l) {
    __builtin_amdgcn_global_load_lds(
        (const __attribute__((address_space(1))) uint32_t*)g,
        (__attribute__((address_space(3))) uint32_t*)l, 16, 0, 0);
}

// XCD-aware swizzle: linear ids round-robin XCDs (id%8); NCOL y-tiles of one
// x-strip land on the same XCD back-to-back -> A-strip L2-resident.
template <int NCOL>
__device__ __forceinline__ void swizzle_xy(int bid, int& x, int& y) {
    int grp  = bid / (8 * NCOL);
    int rem  = bid - grp * (8 * NCOL);
    int base = grp * 8;
    int width = MT - base; if (width > 8) width = 8;
    x = base + rem % width;
    y = rem / width;
}

template <int ACT, bool BIAS, bool OUT_BF16, bool MCHK>
__device__ __forceinline__ void gemm_core(
    const __bf16* __restrict__ A, int lda, const __bf16* __restrict__ W,
    const float* __restrict__ bias, void* __restrict__ Cout, int ldc,
    int K, long Mstore, long blockRow, int blockCol,
    __bf16* __restrict__ smem) {
    __bf16* As = smem;
    __bf16* Ws = smem + 8192;
    const int tid  = threadIdx.x;
    const int wid  = tid >> 6;
    const int lane = tid & 63;
    const int wm = (wid >> 1) << 6;
    const int wn = (wid & 1) << 6;

    f32x4 acc[4][4];
    #pragma unroll
    for (int i = 0; i < 4; ++i)
        #pragma unroll
        for (int j = 0; j < 4; ++j) acc[i][j] = (f32x4)0.0f;

    // staging: wave w owns chunks 4w..4w+3 (1 KB = 8 rows x 128 B each)
    const int srow = lane >> 3;            // row within 8-row chunk
    const int skg  = (lane & 7) ^ srow;    // true k-granule for swizzled slot
    const __bf16* gA[4]; const __bf16* gW[4];
    __bf16 *lA[4], *lW[4];
    #pragma unroll
    for (int i = 0; i < 4; ++i) {
        int c = wid * 4 + i;
        gA[i] = A + (blockRow + c * 8 + srow) * (long)lda + skg * 8;
        gW[i] = W + ((long)blockCol + c * 8 + srow) * (long)K + skg * 8;
        lA[i] = As + c * 512;
        lW[i] = Ws + c * 512;
    }

    const int rA = lane & 15;
    const int q  = lane >> 4;
    const int r7 = rA & 7;

    for (int k0 = 0; k0 < K; k0 += 64) {
        #pragma unroll
        for (int i = 0; i < 4; ++i) gl_lds16(gA[i] + k0, lA[i]);
        #pragma unroll
        for (int i = 0; i < 4; ++i) gl_lds16(gW[i] + k0, lW[i]);
        __syncthreads();

        #pragma unroll
        for (int s = 0; s < 2; ++s) {
            const int slot = ((s * 4 + q) ^ r7) * 8;
            bf16x8 af[4], bf[4];
            #pragma unroll
            for (int mi = 0; mi < 4; ++mi)
                af[mi] = *(const bf16x8*)&As[(wm + mi * 16 + rA) * 64 + slot];
            #pragma unroll
            for (int ni = 0; ni < 4; ++ni)
                bf[ni] = *(const bf16x8*)&Ws[(wn + ni * 16 + rA) * 64 + slot];
            #pragma unroll
            for (int mi = 0; mi < 4; ++mi)
                #pragma unroll
                for (int ni = 0; ni < 4; ++ni)
                    acc[mi][ni] = __builtin_amdgcn_mfma_f32_16x16x32_bf16(
                        af[mi], bf[ni], acc[mi][ni], 0, 0, 0);
        }
        __syncthreads();
    }

    // epilogue: C/D layout col=lane&15, row=(lane>>4)*4+reg
    const int ccol = lane & 15;
    const int crow = (lane >> 4) << 2;
    if (OUT_BF16 && !MCHK) {
        // fast path: stage C tile (128x128 bf16 = 32 KB) in dead As/Ws LDS,
        // then 8 coalesced 16-B stores per thread (1 KB per wave-store).
        #pragma unroll
        for (int mi = 0; mi < 4; ++mi) {
            #pragma unroll
            for (int ni = 0; ni < 4; ++ni) {
                int gc = wn + ni * 16 + ccol;
                float bv = BIAS ? bias[blockCol + gc] : 0.0f;
                #pragma unroll
                for (int r = 0; r < 4; ++r) {
                    float v = acc[mi][ni][r] + bv;
                    if (ACT == 1) v = (v > 0.0f) ? v : 0.1f * v;
                    else if (ACT == 2) v = fmaxf(v, 0.0f);
                    smem[(wm + mi * 16 + crow + r) * 128 + gc] = (__bf16)v;
                }
            }
        }
        __syncthreads();
        #pragma unroll
        for (int i = 0; i < 8; ++i) {
            int o   = (i * 256 + tid) * 8;       // flat elem offset in 128x128
            int row = o >> 7;
            int co  = o & 127;
            *(bf16x8*)((__bf16*)Cout + (blockRow + row) * (long)ldc + blockCol + co) =
                *(const bf16x8*)&smem[o];
        }
    } else {
        #pragma unroll
        for (int mi = 0; mi < 4; ++mi) {
            #pragma unroll
            for (int ni = 0; ni < 4; ++ni) {
                long gr0 = blockRow + wm + mi * 16 + crow;
                int  gc  = blockCol + wn + ni * 16 + ccol;
                float bv = BIAS ? bias[gc] : 0.0f;
                #pragma unroll
                for (int r = 0; r < 4; ++r) {
                    long gr = gr0 + r;
                    if (!MCHK || gr < Mstore) {
                        float v = acc[mi][ni][r] + bv;
                        if (ACT == 1) v = (v > 0.0f) ? v : 0.1f * v;
                        else if (ACT == 2) v = fmaxf(v, 0.0f);
                        if (OUT_BF16) ((__bf16*)Cout)[gr * ldc + gc] = (__bf16)v;
                        else          ((float*)Cout)[gr * ldc + gc] = v;
                    }
                }
            }
        }
    }
}

template <int NCOL, int ACT, bool BIAS, bool OUT_BF16, bool MCHK>
__global__ __launch_bounds__(256) void gemm_bt(
    const __bf16* __restrict__ A, int lda, const __bf16* __restrict__ W,
    const float* __restrict__ bias, void* __restrict__ Cout, int ldc,
    int K, long Mstore) {
    __shared__ __bf16 smem[128 * 128];   // K-loop: As|Ws (32 KB); epilogue: C tile
    int x, y;
    swizzle_xy<NCOL>(blockIdx.x, x, y);
    gemm_core<ACT, BIAS, OUT_BF16, MCHK>(A, lda, W, bias, Cout, ldc, K, Mstore,
                                         (long)x * 128, y * 128, smem);
}

// both heads in one 1D dispatch; swizzled so both heads of one p-strip share
// an XCD. K=128 (each head uses its half of p), lda=256.
__global__ __launch_bounds__(256) void gemm_heads(
    const __bf16* __restrict__ p, const __bf16* __restrict__ wm2,
    const float* __restrict__ b_m2, float* __restrict__ mu,
    const __bf16* __restrict__ wl2, const float* __restrict__ b_l2,
    float* __restrict__ lv) {
    __shared__ __bf16 smem[128 * 128];
    int x, hd;
    swizzle_xy<2>(blockIdx.x, x, hd);
    if (hd == 0)
        gemm_core<0, true, false, true>(p, 256, wm2, b_m2, mu, 128, 128, N_NODES,
                                        (long)x * 128, 0, smem);
    else
        gemm_core<0, true, false, true>(p + 128, 256, wl2, b_l2, lv, 128, 128, N_NODES,
                                        (long)x * 128, 0, smem);
}

extern "C" void kernel_launch(void* const* d_in, const int* in_sizes, int n_in,
                              void* d_out, int out_size, void* d_ws, size_t ws_size,
                              hipStream_t stream) {
    const float* x    = (const float*)d_in[0];
    const int*   ei   = (const int*)d_in[1];
    const float* W_s1 = (const float*)d_in[2];
    const float* b_s1 = (const float*)d_in[3];
    const float* W_s2 = (const float*)d_in[4];
    const float* b_s2 = (const float*)d_in[5];
    const float* W_s3 = (const float*)d_in[6];
    const float* b_s3 = (const float*)d_in[7];
    const float* W_s4 = (const float*)d_in[8];
    const float* b_s4 = (const float*)d_in[9];
    const float* W_m1 = (const float*)d_in[10];
    const float* b_m1 = (const float*)d_in[11];
    const float* W_m2 = (const float*)d_in[12];
    const float* b_m2 = (const float*)d_in[13];
    const float* W_l1 = (const float*)d_in[14];
    const float* b_l1 = (const float*)d_in[15];
    const float* W_l2 = (const float*)d_in[16];
    const float* b_l2 = (const float*)d_in[17];

    char* ws = (char*)d_ws;
    size_t off = 0;
    auto carve = [&](size_t bytes) -> void* {
        void* p = ws + off;
        off = (off + bytes + 255) & ~(size_t)255;
        return p;
    };
    int* cnt  = (int*)carve((size_t)N_NODES * 4);
    int* cur  = (int*)carve((size_t)N_NODES * 4);
    int* ptr  = (int*)carve((size_t)(N_NODES + 1) * 4);
    int* col  = (int*)carve((size_t)E_EDGES * 4);
    int* bsum = (int*)carve(64 * 4);
    int* boff = (int*)carve(64 * 4);
    __bf16* wbuf = (__bf16*)carve((size_t)WTOT * 2);
    __bf16* w1  = wbuf;
    __bf16* w2  = wbuf +  32768;
    __bf16* w3  = wbuf + 294912;
    __bf16* w4  = wbuf + 557056;
    __bf16* wml = wbuf + 819200;   // [W_m1 ; W_l1] rows, 256x512
    __bf16* wm2 = wbuf + 950272;
    __bf16* wl2 = wbuf + 966656;
    __bf16* xb    = (__bf16*)carve((size_t)XN * 2);
    __bf16* agg0b = (__bf16*)carve((size_t)N_PAD * 64 * 2);
    __bf16* B1    = (__bf16*)carve((size_t)N_PAD * 512 * 2);
    __bf16* B2    = (__bf16*)carve((size_t)N_PAD * 512 * 2);

    (void)hipMemsetAsync(cnt, 0, (size_t)N_NODES * 4, stream);
    (void)hipMemsetAsync(cur, 0, (size_t)N_NODES * 4, stream);

    // CSR build
    const int NB = (N_NODES + SCAN_B - 1) / SCAN_B;  // 49
    count_deg<<<E_EDGES / 256, 256, 0, stream>>>(ei, cnt);
    scan_block<<<NB, SCAN_B, 0, stream>>>(cnt, ptr, bsum, N_NODES);
    scan_bsums<<<1, 64, 0, stream>>>(bsum, boff, NB, &ptr[N_NODES]);
    scan_add<<<NB, SCAN_B, 0, stream>>>(ptr, boff, N_NODES);
    fill_csr<<<E_EDGES / 256, 256, 0, stream>>>(ei, ptr, cur, col);

    // one-shot conversions
    cvt_all<<<(XN + WTOT + 255) / 256, 256, 0, stream>>>(
        x, W_s1, W_s2, W_s3, W_s4, W_m1, W_l1, W_m2, W_l2, xb, wbuf);

    // first aggregation
    agg0_gather<<<N_PAD / 4, 256, 0, stream>>>(xb, ptr, col, agg0b);

    // shared MLP: 64->512->512->512->512, lrelu x3, final +b then relu
    gemm_bt<4, 1, true, true, false><<<MT * 4, 256, 0, stream>>>(agg0b, 64, w1, b_s1, B1, 512, 64, N_PAD);
    gemm_bt<4, 1, true, true, false><<<MT * 4, 256, 0, stream>>>(B1, 512, w2, b_s2, B2, 512, 512, N_PAD);
    gemm_bt<4, 1, true, true, false><<<MT * 4, 256, 0, stream>>>(B2, 512, w3, b_s3, B1, 512, 512, N_PAD);
    gemm_bt<4, 2, true, true, false><<<MT * 4, 256, 0, stream>>>(B1, 512, w4, b_s4, B2, 512, 512, N_PAD);

    // project h -> 256 (mu|logvar heads) BEFORE aggregation; bf16 out
    __bf16* t = B1;  // N_PAD x 256 bf16
    gemm_bt<2, 0, false, true, false><<<MT * 2, 256, 0, stream>>>(B2, 512, wml, nullptr, t, 256, 512, N_PAD);

    // second aggregation, fused bias+relu
    __bf16* p = B2;  // N x 256 bf16
    aggt_gather<<<(N_NODES + 3) / 4, 256, 0, stream>>>(t, ptr, col, b_m1, b_l1, p);

    // heads (one swizzled 1D dispatch)
    float* mu = (float*)d_out;
    float* lv = mu + (size_t)N_NODES * 128;
    gemm_heads<<<MT * 2, 256, 0, stream>>>(p, wm2, b_m2, mu, wl2, b_l2, lv);
}